// Round 7
// baseline (311.475 us; speedup 1.0000x reference)
//
#include <hip/hip_runtime.h>
#include <hip/hip_bf16.h>
#include <math.h>

#define NI 1024        // NUM_INPUTS
#define NH 1024        // NUM_HIDDEN
#define H4 4096        // 4*NUM_HIDDEN
#define FGB (-1.0f)
#define LN_EPS 1e-5f
#define NKT 32         // K/32 k-tiles

typedef unsigned short u16;
typedef __attribute__((ext_vector_type(8))) short short8;      // 8 bf16 (MFMA frag)
typedef __attribute__((ext_vector_type(8))) unsigned short ushort8v;
typedef __attribute__((ext_vector_type(16))) float f32x16;     // 32x32 accumulator

__device__ __forceinline__ float bf2f(u16 u) {
    union { unsigned int i; float f; } v; v.i = ((unsigned int)u) << 16; return v.f;
}
__device__ __forceinline__ u16 f2bf(float f) {
    __hip_bfloat16 h = __float2bfloat16(f);   // RNE
    return __builtin_bit_cast(u16, h);
}
__device__ __forceinline__ ushort8v cvt8(float4 lo, float4 hi) {
    ushort8v r;
    r[0] = f2bf(lo.x); r[1] = f2bf(lo.y); r[2] = f2bf(lo.z); r[3] = f2bf(lo.w);
    r[4] = f2bf(hi.x); r[5] = f2bf(hi.y); r[6] = f2bf(hi.z); r[7] = f2bf(hi.w);
    return r;
}
__device__ __forceinline__ float fast_sigmoid(float x) {
    return 1.0f / (1.0f + __expf(-x));
}
__device__ __forceinline__ float fast_tanh(float x) {
    return 1.0f - 2.0f / (__expf(2.0f * x) + 1.0f);
}

// ---------------------------------------------------------------------------
// fp32 [4096 x 1024] -> bf16 in MFMA-fragment-linear order.
// chunk(mtile, kt, kh, lane) holds src[mtile*32 + (lane&31)][kt*32 + kh*16 + (lane>>5)*8 .. +8)
// stored at u16 offset ((mtile*NKT + kt)*2 + kh)*512 + lane*8.
// ---------------------------------------------------------------------------
__global__ __launch_bounds__(256) void shuffle_cast(
    const float* __restrict__ a, const float* __restrict__ b,
    const float* __restrict__ c, const float* __restrict__ d,
    u16* __restrict__ oa, u16* __restrict__ ob,
    u16* __restrict__ oc, u16* __restrict__ od)
{
    const int my = blockIdx.y;
    const float* src = (my == 0) ? a : (my == 1) ? b : (my == 2) ? c : d;
    u16*         dst = (my == 0) ? oa : (my == 1) ? ob : (my == 2) ? oc : od;

    const int lane = threadIdx.x & 63;
    const int wave = threadIdx.x >> 6;
    const int p    = blockIdx.x * 4 + wave;        // mtile*NKT + kt
    const int mtile = p >> 5;                      // NKT = 32
    const int kt    = p & 31;

    const int row  = mtile * 32 + (lane & 31);
    const int colf = kt * 32 + (lane >> 5) * 8;
    const float* s = src + (size_t)row * 1024 + colf;
    u16* o = dst + (size_t)p * 1024 + lane * 8;

    float4 l0 = *(const float4*)(s);
    float4 h0 = *(const float4*)(s + 4);
    float4 l1 = *(const float4*)(s + 16);          // kh=1 -> +16 cols
    float4 h1 = *(const float4*)(s + 20);
    *(ushort8v*)(o)       = cvt8(l0, h0);
    *(ushort8v*)(o + 512) = cvt8(l1, h1);
}

// ---------------------------------------------------------------------------
// C[M,N](bf16) = A @ W^T + bias, A/W pre-shuffled fragment-linear bf16.
// No LDS, no barriers. Block tile 128(m) x 256(n), 4 waves, wave tile
// 64x128 = 2x4 tiles of 32x32x16. Register double-buffered k-pipeline.
// 16 MFMA per 12 loads per k-tile -> 512 pipe-cyc latency cover per wave.
// ---------------------------------------------------------------------------
__global__ __launch_bounds__(256, 2) void gemm_frag(
    const u16* __restrict__ Af0, const u16* __restrict__ Wf0,
    const float* __restrict__ bias0, u16* __restrict__ C0,
    const u16* __restrict__ Af1, const u16* __restrict__ Wf1,
    const float* __restrict__ bias1, u16* __restrict__ C1,
    int N)
{
    const u16*   Af   = blockIdx.z ? Af1 : Af0;
    const u16*   Wf   = blockIdx.z ? Wf1 : Wf0;
    const float* bias = blockIdx.z ? bias1 : bias0;
    u16*         C    = blockIdx.z ? C1 : C0;

    const int lane = threadIdx.x & 63;
    const int wave = threadIdx.x >> 6;
    const int wm   = wave & 1;                 // 0..1 -> 64-row half
    const int wn   = wave >> 1;                // 0..1 -> 128-col half
    const int m0   = blockIdx.y * 128;
    const int n0   = blockIdx.x * 256;

    // per-mtile stride = NKT*2*512 = 32768 u16; per-kt = 1024; per-kh = 512
    const int mt0 = blockIdx.y * 4 + wm * 2;   // 2 mtiles
    const int nt0 = blockIdx.x * 8 + wn * 4;   // 4 ntiles
    const u16* pa0 = Af + (size_t)mt0 * 32768 + lane * 8;
    const u16* pa1 = pa0 + 32768;
    const u16* pb0 = Wf + (size_t)nt0 * 32768 + lane * 8;
    const u16* pb1 = pb0 + 32768;
    const u16* pb2 = pb1 + 32768;
    const u16* pb3 = pb2 + 32768;

    f32x16 acc[2][4];
#pragma unroll
    for (int i = 0; i < 2; ++i)
#pragma unroll
        for (int j = 0; j < 4; ++j)
#pragma unroll
            for (int r = 0; r < 16; ++r)
                acc[i][j][r] = 0.f;

    // frag ring: [buf][A: tm*2+kh (0..3)][B: 4 + tn*2 + kh (4..11)]
    ushort8v f[2][12];

#define LDTILE(buf, kt)                                              \
    do {                                                             \
        const size_t o_ = (size_t)(kt) * 1024;                       \
        f[buf][0]  = *(const ushort8v*)(pa0 + o_);                   \
        f[buf][1]  = *(const ushort8v*)(pa0 + o_ + 512);             \
        f[buf][2]  = *(const ushort8v*)(pa1 + o_);                   \
        f[buf][3]  = *(const ushort8v*)(pa1 + o_ + 512);             \
        f[buf][4]  = *(const ushort8v*)(pb0 + o_);                   \
        f[buf][5]  = *(const ushort8v*)(pb0 + o_ + 512);             \
        f[buf][6]  = *(const ushort8v*)(pb1 + o_);                   \
        f[buf][7]  = *(const ushort8v*)(pb1 + o_ + 512);             \
        f[buf][8]  = *(const ushort8v*)(pb2 + o_);                   \
        f[buf][9]  = *(const ushort8v*)(pb2 + o_ + 512);             \
        f[buf][10] = *(const ushort8v*)(pb3 + o_);                   \
        f[buf][11] = *(const ushort8v*)(pb3 + o_ + 512);             \
    } while (0)

#define MFMA16(buf)                                                                  \
    do {                                                                             \
        _Pragma("unroll")                                                            \
        for (int kh = 0; kh < 2; ++kh)                                               \
            _Pragma("unroll")                                                        \
            for (int tm = 0; tm < 2; ++tm)                                           \
                _Pragma("unroll")                                                    \
                for (int tn = 0; tn < 4; ++tn)                                       \
                    acc[tm][tn] = __builtin_amdgcn_mfma_f32_32x32x16_bf16(           \
                        (short8)f[buf][tm * 2 + kh],                                 \
                        (short8)f[buf][4 + tn * 2 + kh], acc[tm][tn], 0, 0, 0);      \
    } while (0)

    LDTILE(0, 0);
#pragma unroll
    for (int kt2 = 0; kt2 < NKT / 2; ++kt2) {
        const int k1 = kt2 * 2 + 1;
        const int k2 = kt2 * 2 + 2;
        if (k1 < NKT) LDTILE(1, k1);
        MFMA16(0);
        if (k2 < NKT) LDTILE(0, k2);
        MFMA16(1);
    }
#undef LDTILE
#undef MFMA16

    // epilogue: C/D layout col = lane&31, row = (reg&3) + 8*(reg>>2) + 4*(lane>>5)
    const int l31 = lane & 31;
    float bv[4];
#pragma unroll
    for (int tn = 0; tn < 4; ++tn)
        bv[tn] = bias[n0 + wn * 128 + tn * 32 + l31];

    const int rbase = (lane >> 5) * 4;
#pragma unroll
    for (int tm = 0; tm < 2; ++tm)
#pragma unroll
        for (int tn = 0; tn < 4; ++tn) {
            const int col = n0 + wn * 128 + tn * 32 + l31;
#pragma unroll
            for (int reg = 0; reg < 16; ++reg) {
                const int row = m0 + wm * 64 + tm * 32 + (reg & 3) + 8 * (reg >> 2) + rbase;
                C[(size_t)row * N + col] = f2bf(acc[tm][tn][reg] + bv[tn]);
            }
        }
}

// ---------------------------------------------------------------------------
// Pointwise: block-per-row, single HBM pass, bf16 LDS staging (16 KB).
// ---------------------------------------------------------------------------
__global__ __launch_bounds__(256) void lstm_pointwise(
    const u16* __restrict__ i2h, const u16* __restrict__ h2h,
    const float* __restrict__ cx,
    const float* __restrict__ lwx, const float* __restrict__ lbx,
    const float* __restrict__ lwy, const float* __restrict__ lby,
    const float* __restrict__ lwc, const float* __restrict__ lbc,
    float* __restrict__ hx_out, float* __restrict__ cx_out)
{
    __shared__ u16 sX[H4];
    __shared__ u16 sY[H4];
    __shared__ float red[16];

    const int row  = blockIdx.x;
    const int tid  = threadIdx.x;
    const int lane = tid & 63;
    const int wid  = tid >> 6;

    const u16* xr = i2h + (size_t)row * H4;
    const u16* yr = h2h + (size_t)row * H4;

    float sx = 0.f, sxx = 0.f, sy = 0.f, syy = 0.f;
#pragma unroll
    for (int s = 0; s < 2; ++s) {
        const int off = s * 2048 + tid * 8;
        ushort8v xv = *(const ushort8v*)(xr + off);
        ushort8v yv = *(const ushort8v*)(yr + off);
        *(ushort8v*)(sX + off) = xv;
        *(ushort8v*)(sY + off) = yv;
#pragma unroll
        for (int e = 0; e < 8; ++e) {
            float x = bf2f(xv[e]), y = bf2f(yv[e]);
            sx += x; sxx += x * x; sy += y; syy += y * y;
        }
    }
#pragma unroll
    for (int m = 32; m; m >>= 1) {
        sx  += __shfl_xor(sx,  m, 64);
        sxx += __shfl_xor(sxx, m, 64);
        sy  += __shfl_xor(sy,  m, 64);
        syy += __shfl_xor(syy, m, 64);
    }
    if (lane == 0) {
        red[wid] = sx; red[4 + wid] = sxx; red[8 + wid] = sy; red[12 + wid] = syy;
    }
    __syncthreads();
    const float tsx  = red[0] + red[1] + red[2] + red[3];
    const float tsxx = red[4] + red[5] + red[6] + red[7];
    const float tsy  = red[8] + red[9] + red[10] + red[11];
    const float tsyy = red[12] + red[13] + red[14] + red[15];
    __syncthreads();

    const float n1  = (float)H4;
    const float mx  = tsx / n1;
    const float ivx = 1.0f / (sqrtf(fmaxf((tsxx - tsx * tsx / n1) / (n1 - 1.f), 0.f)) + LN_EPS);
    const float my  = tsy / n1;
    const float ivy = 1.0f / (sqrtf(fmaxf((tsyy - tsy * tsy / n1) / (n1 - 1.f), 0.f)) + LN_EPS);

    const int j0 = tid * 4;
    float gate[4][4];
#pragma unroll
    for (int g = 0; g < 4; ++g) {
        ushort4 xv = *(const ushort4*)(sX + g * NH + j0);
        ushort4 yv = *(const ushort4*)(sY + g * NH + j0);
        float4 wxv = *(const float4*)(lwx + g * NH + j0);
        float4 bxv = *(const float4*)(lbx + g * NH + j0);
        float4 wyv = *(const float4*)(lwy + g * NH + j0);
        float4 byv = *(const float4*)(lby + g * NH + j0);
        gate[g][0] = (bf2f(xv.x) - mx) * ivx * wxv.x + bxv.x + (bf2f(yv.x) - my) * ivy * wyv.x + byv.x;
        gate[g][1] = (bf2f(xv.y) - mx) * ivx * wxv.y + bxv.y + (bf2f(yv.y) - my) * ivy * wyv.y + byv.y;
        gate[g][2] = (bf2f(xv.z) - mx) * ivx * wxv.z + bxv.z + (bf2f(yv.z) - my) * ivy * wyv.z + byv.z;
        gate[g][3] = (bf2f(xv.w) - mx) * ivx * wxv.w + bxv.w + (bf2f(yv.w) - my) * ivy * wyv.w + byv.w;
    }

    float4 cxv = *(const float4*)(cx + (size_t)row * NH + j0);
    const float cin[4] = {cxv.x, cxv.y, cxv.z, cxv.w};
    float cvl[4], og[4];
    float sc = 0.f, scc = 0.f;
#pragma unroll
    for (int e = 0; e < 4; ++e) {
        float ing = fast_sigmoid(gate[0][e]);
        float fg  = fast_sigmoid(gate[1][e] + FGB);
        og[e]     = fast_sigmoid(gate[2][e]);
        float tr  = fast_tanh(gate[3][e]);
        float c   = fg * cin[e] + ing * tr;
        cvl[e] = c; sc += c; scc += c * c;
    }
    *(float4*)(cx_out + (size_t)row * NH + j0) = make_float4(cvl[0], cvl[1], cvl[2], cvl[3]);

#pragma unroll
    for (int m = 32; m; m >>= 1) {
        sc  += __shfl_xor(sc,  m, 64);
        scc += __shfl_xor(scc, m, 64);
    }
    if (lane == 0) { red[wid] = sc; red[4 + wid] = scc; }
    __syncthreads();
    const float tsc  = red[0] + red[1] + red[2] + red[3];
    const float tscc = red[4] + red[5] + red[6] + red[7];

    const float nc  = (float)NH;
    const float mc  = tsc / nc;
    const float ivc = 1.0f / (sqrtf(fmaxf((tscc - tsc * tsc / nc) / (nc - 1.f), 0.f)) + LN_EPS);

    float4 wcv = *(const float4*)(lwc + j0);
    float4 bcv = *(const float4*)(lbc + j0);
    float h0 = og[0] * fast_tanh((cvl[0] - mc) * ivc * wcv.x + bcv.x);
    float h1 = og[1] * fast_tanh((cvl[1] - mc) * ivc * wcv.y + bcv.y);
    float h2 = og[2] * fast_tanh((cvl[2] - mc) * ivc * wcv.z + bcv.z);
    float h3 = og[3] * fast_tanh((cvl[3] - mc) * ivc * wcv.w + bcv.w);
    *(float4*)(hx_out + (size_t)row * NH + j0) = make_float4(h0, h1, h2, h3);
}

// ---------------------------------------------------------------------------
extern "C" void kernel_launch(void* const* d_in, const int* in_sizes, int n_in,
                              void* d_out, int out_size, void* d_ws, size_t ws_size,
                              hipStream_t stream) {
    const float* inputs = (const float*)d_in[0];
    const float* hx     = (const float*)d_in[1];
    const float* cx     = (const float*)d_in[2];
    const float* w_i2h  = (const float*)d_in[3];
    const float* b_i2h  = (const float*)d_in[4];
    const float* w_h2h  = (const float*)d_in[5];
    const float* b_h2h  = (const float*)d_in[6];
    const float* lwx    = (const float*)d_in[7];
    const float* lbx    = (const float*)d_in[8];
    const float* lwy    = (const float*)d_in[9];
    const float* lby    = (const float*)d_in[10];
    const float* lwc    = (const float*)d_in[11];
    const float* lbc    = (const float*)d_in[12];

    const int B = in_sizes[0] / NI;                // 4096

    u16* a_fr   = (u16*)d_ws;                      // fragment-linear, 8 MB each
    u16* hx_fr  = a_fr   + (size_t)B * NI;
    u16* wi_fr  = hx_fr  + (size_t)B * NH;
    u16* wh_fr  = wi_fr  + (size_t)H4 * NI;
    u16* i2h_bf = wh_fr  + (size_t)H4 * NH;        // row-major outputs, 32 MB each
    u16* h2h_bf = i2h_bf + (size_t)B * H4;

    float* hx_out = (float*)d_out;
    float* cx_out = hx_out + (size_t)B * NH;

    shuffle_cast<<<dim3(1024, 4), dim3(256), 0, stream>>>(
        inputs, hx, w_i2h, w_h2h, a_fr, hx_fr, wi_fr, wh_fr);

    gemm_frag<<<dim3(H4 / 256, B / 128, 2), dim3(256), 0, stream>>>(
        a_fr, wi_fr, b_i2h, i2h_bf,
        hx_fr, wh_fr, b_h2h, h2h_bf,
        H4);

    lstm_pointwise<<<dim3(B), dim3(256), 0, stream>>>(
        i2h_bf, h2h_bf, cx, lwx, lbx, lwy, lby, lwc, lbc, hx_out, cx_out);
}

// Round 8
// 257.507 us; speedup vs baseline: 1.2096x; 1.2096x over previous
//
#include <hip/hip_runtime.h>
#include <hip/hip_bf16.h>
#include <math.h>

#define NI 1024        // NUM_INPUTS
#define NH 1024        // NUM_HIDDEN
#define H4 4096        // 4*NUM_HIDDEN
#define FGB (-1.0f)
#define LN_EPS 1e-5f
#define NKT 32         // K/32 k-tiles

typedef unsigned short u16;
typedef __attribute__((ext_vector_type(8))) short short8;      // 8 bf16 (MFMA frag)
typedef __attribute__((ext_vector_type(8))) unsigned short ushort8v;
typedef __attribute__((ext_vector_type(16))) float f32x16;     // 32x32 accumulator

__device__ __forceinline__ float bf2f(u16 u) {
    union { unsigned int i; float f; } v; v.i = ((unsigned int)u) << 16; return v.f;
}
__device__ __forceinline__ u16 f2bf(float f) {
    __hip_bfloat16 h = __float2bfloat16(f);   // RNE
    return __builtin_bit_cast(u16, h);
}
__device__ __forceinline__ ushort8v cvt8(float4 lo, float4 hi) {
    ushort8v r;
    r[0] = f2bf(lo.x); r[1] = f2bf(lo.y); r[2] = f2bf(lo.z); r[3] = f2bf(lo.w);
    r[4] = f2bf(hi.x); r[5] = f2bf(hi.y); r[6] = f2bf(hi.z); r[7] = f2bf(hi.w);
    return r;
}
__device__ __forceinline__ float fast_sigmoid(float x) {
    return 1.0f / (1.0f + __expf(-x));
}
__device__ __forceinline__ float fast_tanh(float x) {
    return 1.0f - 2.0f / (__expf(2.0f * x) + 1.0f);
}

// ---------------------------------------------------------------------------
// fp32 [4096 x 1024] -> bf16 in MFMA-fragment-linear order.
// chunk(mtile, kt, kh, lane) holds src[mtile*32 + (lane&31)][kt*32 + kh*16 + (lane>>5)*8 .. +8)
// stored at u16 offset ((mtile*NKT + kt)*2 + kh)*512 + lane*8.
// ---------------------------------------------------------------------------
__global__ __launch_bounds__(256) void shuffle_cast(
    const float* __restrict__ a, const float* __restrict__ b,
    const float* __restrict__ c, const float* __restrict__ d,
    u16* __restrict__ oa, u16* __restrict__ ob,
    u16* __restrict__ oc, u16* __restrict__ od)
{
    const int my = blockIdx.y;
    const float* src = (my == 0) ? a : (my == 1) ? b : (my == 2) ? c : d;
    u16*         dst = (my == 0) ? oa : (my == 1) ? ob : (my == 2) ? oc : od;

    const int lane = threadIdx.x & 63;
    const int wave = threadIdx.x >> 6;
    const int p    = blockIdx.x * 4 + wave;        // mtile*NKT + kt
    const int mtile = p >> 5;                      // NKT = 32
    const int kt    = p & 31;

    const int row  = mtile * 32 + (lane & 31);
    const int colf = kt * 32 + (lane >> 5) * 8;
    const float* s = src + (size_t)row * 1024 + colf;
    u16* o = dst + (size_t)p * 1024 + lane * 8;

    float4 l0 = *(const float4*)(s);
    float4 h0 = *(const float4*)(s + 4);
    float4 l1 = *(const float4*)(s + 16);          // kh=1 -> +16 cols
    float4 h1 = *(const float4*)(s + 20);
    *(ushort8v*)(o)       = cvt8(l0, h0);
    *(ushort8v*)(o + 512) = cvt8(l1, h1);
}

// ---------------------------------------------------------------------------
// C[M,N](bf16) = A @ W^T + bias, A/W pre-shuffled fragment-linear bf16.
// No LDS, no barriers. Block 128x128, 4 waves, 64x64 wave tile (2x2 of
// 32x32x16). THREE-deep register prefetch ring: lookahead 2 k-tiles
// (~512 own-wave cyc; ~1024 wall at 2 waves/SIMD) to cover HBM-miss latency.
// ---------------------------------------------------------------------------
__global__ __launch_bounds__(256) void gemm_frag(
    const u16* __restrict__ Af0, const u16* __restrict__ Wf0,
    const float* __restrict__ bias0, u16* __restrict__ C0,
    const u16* __restrict__ Af1, const u16* __restrict__ Wf1,
    const float* __restrict__ bias1, u16* __restrict__ C1,
    int N)
{
    const u16*   Af   = blockIdx.z ? Af1 : Af0;
    const u16*   Wf   = blockIdx.z ? Wf1 : Wf0;
    const float* bias = blockIdx.z ? bias1 : bias0;
    u16*         C    = blockIdx.z ? C1 : C0;

    const int lane = threadIdx.x & 63;
    const int wave = threadIdx.x >> 6;
    const int wm   = wave & 1;
    const int wn   = wave >> 1;
    const int m0   = blockIdx.y * 128;
    const int n0   = blockIdx.x * 128;

    // per-mtile stride = NKT*2*512 = 32768 u16; per-kt = 1024; per-kh = 512
    const int mt0 = blockIdx.y * 4 + wm * 2;
    const int nt0 = blockIdx.x * 4 + wn * 2;
    const u16* pa0 = Af + (size_t)mt0 * 32768 + lane * 8;
    const u16* pa1 = pa0 + 32768;
    const u16* pb0 = Wf + (size_t)nt0 * 32768 + lane * 8;
    const u16* pb1 = pb0 + 32768;

    f32x16 acc[2][2];
#pragma unroll
    for (int i = 0; i < 2; ++i)
#pragma unroll
        for (int j = 0; j < 2; ++j)
#pragma unroll
            for (int r = 0; r < 16; ++r)
                acc[i][j][r] = 0.f;

    // frag ring: [buf][0..3]=A(tm0/kh0, tm0/kh1, tm1/kh0, tm1/kh1), [4..7]=B
    ushort8v f[3][8];

#define LDTILE(buf, kt)                                              \
    do {                                                             \
        const size_t o_ = (size_t)(kt) * 1024;                       \
        f[buf][0] = *(const ushort8v*)(pa0 + o_);                    \
        f[buf][1] = *(const ushort8v*)(pa0 + o_ + 512);              \
        f[buf][2] = *(const ushort8v*)(pa1 + o_);                    \
        f[buf][3] = *(const ushort8v*)(pa1 + o_ + 512);              \
        f[buf][4] = *(const ushort8v*)(pb0 + o_);                    \
        f[buf][5] = *(const ushort8v*)(pb0 + o_ + 512);              \
        f[buf][6] = *(const ushort8v*)(pb1 + o_);                    \
        f[buf][7] = *(const ushort8v*)(pb1 + o_ + 512);              \
    } while (0)

#define MFMA8(buf)                                                                              \
    do {                                                                                        \
        acc[0][0] = __builtin_amdgcn_mfma_f32_32x32x16_bf16(                                    \
            (short8)f[buf][0], (short8)f[buf][4], acc[0][0], 0, 0, 0);                          \
        acc[0][1] = __builtin_amdgcn_mfma_f32_32x32x16_bf16(                                    \
            (short8)f[buf][0], (short8)f[buf][6], acc[0][1], 0, 0, 0);                          \
        acc[1][0] = __builtin_amdgcn_mfma_f32_32x32x16_bf16(                                    \
            (short8)f[buf][2], (short8)f[buf][4], acc[1][0], 0, 0, 0);                          \
        acc[1][1] = __builtin_amdgcn_mfma_f32_32x32x16_bf16(                                    \
            (short8)f[buf][2], (short8)f[buf][6], acc[1][1], 0, 0, 0);                          \
        acc[0][0] = __builtin_amdgcn_mfma_f32_32x32x16_bf16(                                    \
            (short8)f[buf][1], (short8)f[buf][5], acc[0][0], 0, 0, 0);                          \
        acc[0][1] = __builtin_amdgcn_mfma_f32_32x32x16_bf16(                                    \
            (short8)f[buf][1], (short8)f[buf][7], acc[0][1], 0, 0, 0);                          \
        acc[1][0] = __builtin_amdgcn_mfma_f32_32x32x16_bf16(                                    \
            (short8)f[buf][3], (short8)f[buf][5], acc[1][0], 0, 0, 0);                          \
        acc[1][1] = __builtin_amdgcn_mfma_f32_32x32x16_bf16(                                    \
            (short8)f[buf][3], (short8)f[buf][7], acc[1][1], 0, 0, 0);                          \
    } while (0)

    LDTILE(0, 0);
    LDTILE(1, 1);
#pragma unroll
    for (int kt = 0; kt < NKT; ++kt) {
        const int cur = kt % 3;
        const int nxt = (kt + 2) % 3;
        if (kt + 2 < NKT) LDTILE(nxt, kt + 2);
        MFMA8(cur);
    }
#undef LDTILE
#undef MFMA8

    // epilogue: C/D layout col = lane&31, row = (reg&3) + 8*(reg>>2) + 4*(lane>>5)
    // store order reg-major, tn-inner so the two 64B halves of each 128B
    // C line (tn=0 cols 0..31, tn=1 cols 32..63) are written back-to-back.
    const int l31 = lane & 31;
    float bv[2];
#pragma unroll
    for (int tn = 0; tn < 2; ++tn)
        bv[tn] = bias[n0 + wn * 64 + tn * 32 + l31];

    const int rbase = (lane >> 5) * 4;
#pragma unroll
    for (int tm = 0; tm < 2; ++tm)
#pragma unroll
        for (int reg = 0; reg < 16; ++reg) {
            const int row = m0 + wm * 64 + tm * 32 + (reg & 3) + 8 * (reg >> 2) + rbase;
#pragma unroll
            for (int tn = 0; tn < 2; ++tn) {
                const int col = n0 + wn * 64 + tn * 32 + l31;
                C[(size_t)row * N + col] = f2bf(acc[tm][tn][reg] + bv[tn]);
            }
        }
}

// ---------------------------------------------------------------------------
// Pointwise: block-per-row, single HBM pass, bf16 LDS staging (16 KB).
// ---------------------------------------------------------------------------
__global__ __launch_bounds__(256) void lstm_pointwise(
    const u16* __restrict__ i2h, const u16* __restrict__ h2h,
    const float* __restrict__ cx,
    const float* __restrict__ lwx, const float* __restrict__ lbx,
    const float* __restrict__ lwy, const float* __restrict__ lby,
    const float* __restrict__ lwc, const float* __restrict__ lbc,
    float* __restrict__ hx_out, float* __restrict__ cx_out)
{
    __shared__ u16 sX[H4];
    __shared__ u16 sY[H4];
    __shared__ float red[16];

    const int row  = blockIdx.x;
    const int tid  = threadIdx.x;
    const int lane = tid & 63;
    const int wid  = tid >> 6;

    const u16* xr = i2h + (size_t)row * H4;
    const u16* yr = h2h + (size_t)row * H4;

    float sx = 0.f, sxx = 0.f, sy = 0.f, syy = 0.f;
#pragma unroll
    for (int s = 0; s < 2; ++s) {
        const int off = s * 2048 + tid * 8;
        ushort8v xv = *(const ushort8v*)(xr + off);
        ushort8v yv = *(const ushort8v*)(yr + off);
        *(ushort8v*)(sX + off) = xv;
        *(ushort8v*)(sY + off) = yv;
#pragma unroll
        for (int e = 0; e < 8; ++e) {
            float x = bf2f(xv[e]), y = bf2f(yv[e]);
            sx += x; sxx += x * x; sy += y; syy += y * y;
        }
    }
#pragma unroll
    for (int m = 32; m; m >>= 1) {
        sx  += __shfl_xor(sx,  m, 64);
        sxx += __shfl_xor(sxx, m, 64);
        sy  += __shfl_xor(sy,  m, 64);
        syy += __shfl_xor(syy, m, 64);
    }
    if (lane == 0) {
        red[wid] = sx; red[4 + wid] = sxx; red[8 + wid] = sy; red[12 + wid] = syy;
    }
    __syncthreads();
    const float tsx  = red[0] + red[1] + red[2] + red[3];
    const float tsxx = red[4] + red[5] + red[6] + red[7];
    const float tsy  = red[8] + red[9] + red[10] + red[11];
    const float tsyy = red[12] + red[13] + red[14] + red[15];
    __syncthreads();

    const float n1  = (float)H4;
    const float mx  = tsx / n1;
    const float ivx = 1.0f / (sqrtf(fmaxf((tsxx - tsx * tsx / n1) / (n1 - 1.f), 0.f)) + LN_EPS);
    const float my  = tsy / n1;
    const float ivy = 1.0f / (sqrtf(fmaxf((tsyy - tsy * tsy / n1) / (n1 - 1.f), 0.f)) + LN_EPS);

    const int j0 = tid * 4;
    float gate[4][4];
#pragma unroll
    for (int g = 0; g < 4; ++g) {
        ushort4 xv = *(const ushort4*)(sX + g * NH + j0);
        ushort4 yv = *(const ushort4*)(sY + g * NH + j0);
        float4 wxv = *(const float4*)(lwx + g * NH + j0);
        float4 bxv = *(const float4*)(lbx + g * NH + j0);
        float4 wyv = *(const float4*)(lwy + g * NH + j0);
        float4 byv = *(const float4*)(lby + g * NH + j0);
        gate[g][0] = (bf2f(xv.x) - mx) * ivx * wxv.x + bxv.x + (bf2f(yv.x) - my) * ivy * wyv.x + byv.x;
        gate[g][1] = (bf2f(xv.y) - mx) * ivx * wxv.y + bxv.y + (bf2f(yv.y) - my) * ivy * wyv.y + byv.y;
        gate[g][2] = (bf2f(xv.z) - mx) * ivx * wxv.z + bxv.z + (bf2f(yv.z) - my) * ivy * wyv.z + byv.z;
        gate[g][3] = (bf2f(xv.w) - mx) * ivx * wxv.w + bxv.w + (bf2f(yv.w) - my) * ivy * wyv.w + byv.w;
    }

    float4 cxv = *(const float4*)(cx + (size_t)row * NH + j0);
    const float cin[4] = {cxv.x, cxv.y, cxv.z, cxv.w};
    float cvl[4], og[4];
    float sc = 0.f, scc = 0.f;
#pragma unroll
    for (int e = 0; e < 4; ++e) {
        float ing = fast_sigmoid(gate[0][e]);
        float fg  = fast_sigmoid(gate[1][e] + FGB);
        og[e]     = fast_sigmoid(gate[2][e]);
        float tr  = fast_tanh(gate[3][e]);
        float c   = fg * cin[e] + ing * tr;
        cvl[e] = c; sc += c; scc += c * c;
    }
    *(float4*)(cx_out + (size_t)row * NH + j0) = make_float4(cvl[0], cvl[1], cvl[2], cvl[3]);

#pragma unroll
    for (int m = 32; m; m >>= 1) {
        sc  += __shfl_xor(sc,  m, 64);
        scc += __shfl_xor(scc, m, 64);
    }
    if (lane == 0) { red[wid] = sc; red[4 + wid] = scc; }
    __syncthreads();
    const float tsc  = red[0] + red[1] + red[2] + red[3];
    const float tscc = red[4] + red[5] + red[6] + red[7];

    const float nc  = (float)NH;
    const float mc  = tsc / nc;
    const float ivc = 1.0f / (sqrtf(fmaxf((tscc - tsc * tsc / nc) / (nc - 1.f), 0.f)) + LN_EPS);

    float4 wcv = *(const float4*)(lwc + j0);
    float4 bcv = *(const float4*)(lbc + j0);
    float h0 = og[0] * fast_tanh((cvl[0] - mc) * ivc * wcv.x + bcv.x);
    float h1 = og[1] * fast_tanh((cvl[1] - mc) * ivc * wcv.y + bcv.y);
    float h2 = og[2] * fast_tanh((cvl[2] - mc) * ivc * wcv.z + bcv.z);
    float h3 = og[3] * fast_tanh((cvl[3] - mc) * ivc * wcv.w + bcv.w);
    *(float4*)(hx_out + (size_t)row * NH + j0) = make_float4(h0, h1, h2, h3);
}

// ---------------------------------------------------------------------------
extern "C" void kernel_launch(void* const* d_in, const int* in_sizes, int n_in,
                              void* d_out, int out_size, void* d_ws, size_t ws_size,
                              hipStream_t stream) {
    const float* inputs = (const float*)d_in[0];
    const float* hx     = (const float*)d_in[1];
    const float* cx     = (const float*)d_in[2];
    const float* w_i2h  = (const float*)d_in[3];
    const float* b_i2h  = (const float*)d_in[4];
    const float* w_h2h  = (const float*)d_in[5];
    const float* b_h2h  = (const float*)d_in[6];
    const float* lwx    = (const float*)d_in[7];
    const float* lbx    = (const float*)d_in[8];
    const float* lwy    = (const float*)d_in[9];
    const float* lby    = (const float*)d_in[10];
    const float* lwc    = (const float*)d_in[11];
    const float* lbc    = (const float*)d_in[12];

    const int B = in_sizes[0] / NI;                // 4096

    u16* a_fr   = (u16*)d_ws;                      // fragment-linear, 8 MB each
    u16* hx_fr  = a_fr   + (size_t)B * NI;
    u16* wi_fr  = hx_fr  + (size_t)B * NH;
    u16* wh_fr  = wi_fr  + (size_t)H4 * NI;
    u16* i2h_bf = wh_fr  + (size_t)H4 * NH;        // row-major outputs, 32 MB each
    u16* h2h_bf = i2h_bf + (size_t)B * H4;

    float* hx_out = (float*)d_out;
    float* cx_out = hx_out + (size_t)B * NH;

    shuffle_cast<<<dim3(1024, 4), dim3(256), 0, stream>>>(
        inputs, hx, w_i2h, w_h2h, a_fr, hx_fr, wi_fr, wh_fr);

    gemm_frag<<<dim3(H4 / 128, B / 128, 2), dim3(256), 0, stream>>>(
        a_fr, wi_fr, b_i2h, i2h_bf,
        hx_fr, wh_fr, b_h2h, h2h_bf,
        H4);

    lstm_pointwise<<<dim3(B), dim3(256), 0, stream>>>(
        i2h_bf, h2h_bf, cx, lwx, lbx, lwy, lby, lwc, lbc, hx_out, cx_out);
}